// Round 8
// baseline (3987.711 us; speedup 1.0000x reference)
//
#include <hip/hip_runtime.h>

#define NFULL 33024
#define FPS_T 1024
#define BST   99072    // per-batch stride in XYZ SoA: 3*33024

// ---- x1[b,o,k] = sum_i f[b,i] * ps_w[i,o,k] + ps_b[o] ; col = o*256+k ----
__global__ void k_ps(const float* __restrict__ feat,
                     const float* __restrict__ psw,
                     const float* __restrict__ psb,
                     float* __restrict__ out)
{
    __shared__ float fs[16384];   // all of f (32x512), 64 KB
    const int tid = threadIdx.x;
    for (int k = tid; k < 16384; k += 256) fs[k] = feat[k];
    __syncthreads();
    const int col = blockIdx.x * 256 + tid;    // 0..32767
    float acc[32];
    #pragma unroll
    for (int b = 0; b < 32; ++b) acc[b] = 0.f;
    for (int i = 0; i < 512; i += 4) {
        const float w0 = psw[(i+0)*32768 + col];
        const float w1 = psw[(i+1)*32768 + col];
        const float w2 = psw[(i+2)*32768 + col];
        const float w3 = psw[(i+3)*32768 + col];
        #pragma unroll
        for (int b = 0; b < 32; ++b) {
            const float4 f4 = *(const float4*)&fs[b*512 + i];
            acc[b] += f4.x*w0 + f4.y*w1 + f4.z*w2 + f4.w*w3;
        }
    }
    const float bias = psb[col >> 8];
    #pragma unroll
    for (int b = 0; b < 32; ++b) out[b*32768 + col] = acc[b] + bias;
}

// ---- fb[wsel][b,o] = sum_{i<512} f[b,i] * w[o*640 + 128 + i]  (fr-fold) ----
__global__ void k_fb(const float* __restrict__ feat,
                     const float* __restrict__ wa, const float* __restrict__ wb,
                     const float* __restrict__ wc, const float* __restrict__ wd,
                     float* __restrict__ fb)
{
    const int tid = blockIdx.x * 256 + threadIdx.x;  // 0..16383
    const int wsel = tid >> 12;
    const int r = tid & 4095;
    const int b = r >> 7, o = r & 127;
    const float* w = (wsel == 0 ? wa : wsel == 1 ? wb : wsel == 2 ? wc : wd) + o*640 + 128;
    const float* f = feat + b*512;
    float acc = 0.f;
    for (int i = 0; i < 512; i += 4) {
        const float4 wv = *(const float4*)(w + i);
        const float4 fv = *(const float4*)(f + i);
        acc += wv.x*fv.x + wv.y*fv.y + wv.z*fv.z + wv.w*fv.w;
    }
    fb[tid] = acc;
}

// ---- out[b,o,n] = relu?( sum_i w[o,i]*x[b,i,n] + bias[o] + fb[b,o] + add[b,o,n] )
__global__ void k_conv(const float* __restrict__ x,
                       const float* __restrict__ w,
                       const float* __restrict__ bias,
                       const float* __restrict__ fb,
                       const float* __restrict__ add,
                       float* __restrict__ out,
                       const int O, const int K, const int ldw, const int relu)
{
    const int bo = blockIdx.x;
    const int b = bo / O;
    const int o = bo - b * O;
    const int n = threadIdx.x;
    const float* __restrict__ wr = w + o * ldw;
    const float* __restrict__ xb = x + (b * K) * 256 + n;
    float acc = 0.f;
    for (int i = 0; i < K; i += 4) {
        const float4 wv = *(const float4*)(wr + i);
        acc += wv.x * xb[(i+0) << 8];
        acc += wv.y * xb[(i+1) << 8];
        acc += wv.z * xb[(i+2) << 8];
        acc += wv.w * xb[(i+3) << 8];
    }
    acc += bias[o];
    if (fb)   acc += fb[b * O + o];
    if (add)  acc += add[bo * 256 + n];
    if (relu) acc = fmaxf(acc, 0.f);
    out[bo * 256 + n] = acc;
}

// ---- pcd transpose -> d_out ; completion points -> XYZ SoA [0,256) ----
__global__ void k_pcd(const float* __restrict__ comp,
                      float* __restrict__ pcd_out,
                      float* __restrict__ XYZ)
{
    const int tid = blockIdx.x * 256 + threadIdx.x;  // 0..8191
    const int b = tid >> 8, n = tid & 255;
    const float cx = comp[(b*3+0)*256 + n];
    const float cy = comp[(b*3+1)*256 + n];
    const float cz = comp[(b*3+2)*256 + n];
    pcd_out[tid*3+0] = cx; pcd_out[tid*3+1] = cy; pcd_out[tid*3+2] = cz;
    float* Xb = XYZ + b*BST;
    Xb[n]           = cx;
    Xb[33024  + n]  = cy;
    Xb[66048  + n]  = cz;
}

// ---- partial (AoS) -> XYZ SoA [256,33024) per batch (bitwise) ----
__global__ void k_copy(const float* __restrict__ partial, float* __restrict__ XYZ)
{
    const int p = blockIdx.x*256 + threadIdx.x;   // 0..1048575 (32*32768)
    const int b = p >> 15, i = p & 32767;
    const float x = partial[p*3+0];
    const float y = partial[p*3+1];
    const float z = partial[p*3+2];
    float* Xb = XYZ + b*BST;
    Xb[256 + i]          = x;
    Xb[33024 + 256 + i]  = y;
    Xb[66048 + 256 + i]  = z;
}

// ================= farthest point sampling =================
// One 1024-thread block per batch: 16 waves = 4 waves/SIMD (2x the TLP of
// the T=512 variant, which measured ~50% exposed latency). Per-thread state
// is only the 33 mutable d-scalars + transient float4s (~60 VGPR), fitting
// even the allocator's 64-VGPR preference for this shape; waves_per_eu(4,4)
// raises the cap to 128 as headroom. FBODY tracks a tiny code (jo*4+c,
// inline-const in v_cndmask, 0..35) instead of a full index; decoded once
// per step. Ascending code == ascending global index per thread, so the
// strict-> scan + min-index tie-break reproduce np.argmax first-max exactly.
// z in LDS (129KB); x/y streamed from L2-resident SoA.

#define REP8(M) M(0) M(1) M(2) M(3) M(4) M(5) M(6) M(7)

#define FPS_DECL(jo) float d##jo##_0 = 1.0e10f, d##jo##_1 = 1.0e10f, \
                           d##jo##_2 = 1.0e10f, d##jo##_3 = 1.0e10f;

#define FBODY(xx, yy, zz, dd, cc) { \
    const float dx = __fsub_rn((xx), lx); \
    const float dy = __fsub_rn((yy), ly); \
    const float dz = __fsub_rn((zz), lz); \
    const float dist = __fadd_rn(__fadd_rn(__fmul_rn(dx,dx), __fmul_rn(dy,dy)), \
                                 __fmul_rn(dz,dz)); \
    dd = fminf(dd, dist); \
    if (dd > bestv) { bestv = dd; bestc = (cc); } }

#define FPS_GRP(jo) { \
    const float4 x4 = *(const float4*)(Xb + (jo)*4096 + t4); \
    const float4 y4 = *(const float4*)(Yb + (jo)*4096 + t4); \
    const float4 z4 = *(const float4*)(zs + (jo)*4096 + t4); \
    FBODY(x4.x, y4.x, z4.x, d##jo##_0, (jo)*4 + 0) \
    FBODY(x4.y, y4.y, z4.y, d##jo##_1, (jo)*4 + 1) \
    FBODY(x4.z, y4.z, z4.z, d##jo##_2, (jo)*4 + 2) \
    FBODY(x4.w, y4.w, z4.w, d##jo##_3, (jo)*4 + 3) }

__attribute__((amdgpu_waves_per_eu(4, 4)))
__global__ void __launch_bounds__(FPS_T)
k_fps(const float* __restrict__ XYZ, float* __restrict__ outp)
{
    __shared__ __align__(16) float zs[NFULL];   // 132,096 B
    __shared__ float redv[2][16];
    __shared__ int   redi[2][16];

    const int b = blockIdx.x;
    const int t = threadIdx.x;
    const int t4 = t << 2;
    const float* __restrict__ Xb = XYZ + b*BST;
    const float* __restrict__ Yb = Xb + 33024;
    const float* __restrict__ Zb = Xb + 66048;
    const float NEG = -__builtin_inff();

    for (int k = t; k < NFULL; k += FPS_T) zs[k] = Zb[k];

    REP8(FPS_DECL)
    float dt_0 = 1.0e10f, dt_1 = 1.0e10f, dt_2 = 1.0e10f, dt_3 = 1.0e10f;
    __syncthreads();

    int last = 0;
    float* __restrict__ po = outp + b * (512*3);
    for (int s = 0; s < 512; ++s) {
        const float lx = Xb[last];
        const float ly = Yb[last];
        const float lz = zs[last];            // bitwise == Zb[last]
        if (t == 0) { po[s*3+0] = lx; po[s*3+1] = ly; po[s*3+2] = lz; }
        if (s == 511) break;

        float bestv = NEG;
        int   bestc = 0x7FFFFFFF;
        // np order: dist = (dx*dx + dy*dy) + dz*dz, no fma; strict-> scan
        REP8(FPS_GRP)
        if (t < 64) {   // tail points 32768..33023 (64 threads x 4), code 32..35
            const float4 x4 = *(const float4*)(Xb + 32768 + t4);
            const float4 y4 = *(const float4*)(Yb + 32768 + t4);
            const float4 z4 = *(const float4*)(zs + 32768 + t4);
            FBODY(x4.x, y4.x, z4.x, dt_0, 32)
            FBODY(x4.y, y4.y, z4.y, dt_1, 33)
            FBODY(x4.z, y4.z, z4.z, dt_2, 34)
            FBODY(x4.w, y4.w, z4.w, dt_3, 35)
        }
        // decode code -> global point index (same formula covers tail:
        // (32>>2)<<12 = 32768)
        int besti = ((bestc >> 2) << 12) + t4 + (bestc & 3);

        // wave (64-lane) argmax reduce, min-index tie-break
        #pragma unroll
        for (int m = 1; m < 64; m <<= 1) {
            const float ov = __shfl_xor(bestv, m, 64);
            const int   oi = __shfl_xor(besti, m, 64);
            if (ov > bestv || (ov == bestv && oi < besti)) { bestv = ov; besti = oi; }
        }
        const int bank = s & 1;
        if ((t & 63) == 0) { redv[bank][t >> 6] = bestv; redi[bank][t >> 6] = besti; }
        __syncthreads();
        // every wave redundantly reduces the 16 partials (no 2nd barrier;
        // bank is step-parity double-buffered)
        {
            const int lane = t & 63;
            float v = (lane < 16) ? redv[bank][lane] : NEG;
            int   i = (lane < 16) ? redi[bank][lane] : 0x7FFFFFFF;
            #pragma unroll
            for (int m = 1; m < 16; m <<= 1) {
                const float ov = __shfl_xor(v, m, 64);
                const int   oi = __shfl_xor(i, m, 64);
                if (ov > v || (ov == v && oi < i)) { v = ov; i = oi; }
            }
            last = __shfl(i, 0, 64);
        }
    }
}

extern "C" void kernel_launch(void* const* d_in, const int* in_sizes, int n_in,
                              void* d_out, int out_size, void* d_ws, size_t ws_size,
                              hipStream_t stream)
{
    const float* feat    = (const float*)d_in[0];
    const float* partial = (const float*)d_in[1];
    const float* ps_w    = (const float*)d_in[2];
    const float* ps_b    = (const float*)d_in[3];
    const float* m1_w1   = (const float*)d_in[4];
    const float* m1_b1   = (const float*)d_in[5];
    const float* m1_w2   = (const float*)d_in[6];
    const float* m1_b2   = (const float*)d_in[7];
    const float* m1_ws   = (const float*)d_in[8];
    const float* m1_bs   = (const float*)d_in[9];
    const float* m2_w1   = (const float*)d_in[10];
    const float* m2_b1   = (const float*)d_in[11];
    const float* m2_w2   = (const float*)d_in[12];
    const float* m2_b2   = (const float*)d_in[13];
    const float* m2_ws   = (const float*)d_in[14];
    const float* m2_bs   = (const float*)d_in[15];
    const float* m3_w1   = (const float*)d_in[16];
    const float* m3_b1   = (const float*)d_in[17];
    const float* m3_w2   = (const float*)d_in[18];
    const float* m3_b2   = (const float*)d_in[19];
    const float* m3_ws   = (const float*)d_in[20];
    const float* m3_bs   = (const float*)d_in[21];
    const float* m4_w1   = (const float*)d_in[22];
    const float* m4_b1   = (const float*)d_in[23];
    const float* m4_w2   = (const float*)d_in[24];
    const float* m4_b2   = (const float*)d_in[25];

    float* ws = (float*)d_ws;
    float* XYZ = ws;              // 32*3*33024 = 3,170,304 floats (SoA per batch)
    float* A  = ws + 3170304;     // 1,048,576
    float* B  = ws + 4218880;     // 1,048,576
    float* C  = ws + 5267456;     // 1,048,576
    float* FB = ws + 6316032;     // 4*4096 (m1_w1, m1_ws, m3_w1, m3_ws folds)

    float* out = (float*)d_out;   // [0,24576) pcd ; [24576,73728) p0

    k_ps  <<<128,  256, 0, stream>>>(feat, ps_w, ps_b, A);
    k_fb  <<<64,   256, 0, stream>>>(feat, m1_w1, m1_ws, m3_w1, m3_ws, FB);
    k_copy<<<4096, 256, 0, stream>>>(partial, XYZ);

    // m1 (fr folded into FB)
    k_conv<<<32*128, 256, 0, stream>>>(A, m1_w1, m1_b1, FB,       nullptr, B, 128, 128, 640, 1);
    k_conv<<<32*128, 256, 0, stream>>>(A, m1_ws, m1_bs, FB+4096,  nullptr, C, 128, 128, 640, 0);
    k_conv<<<32*128, 256, 0, stream>>>(B, m1_w2, m1_b2, nullptr,  C,       A, 128, 128, 128, 0);
    // m2
    k_conv<<<32*64,  256, 0, stream>>>(A, m2_w1, m2_b1, nullptr,  nullptr, B, 64,  128, 128, 1);
    k_conv<<<32*128, 256, 0, stream>>>(A, m2_ws, m2_bs, nullptr,  nullptr, C, 128, 128, 128, 0);
    k_conv<<<32*128, 256, 0, stream>>>(B, m2_w2, m2_b2, nullptr,  C,       A, 128, 64,  64,  0);
    // m3 (fr folded)
    k_conv<<<32*128, 256, 0, stream>>>(A, m3_w1, m3_b1, FB+8192,  nullptr, B, 128, 128, 640, 1);
    k_conv<<<32*128, 256, 0, stream>>>(A, m3_ws, m3_bs, FB+12288, nullptr, C, 128, 128, 640, 0);
    k_conv<<<32*128, 256, 0, stream>>>(B, m3_w2, m3_b2, nullptr,  C,       A, 128, 128, 128, 0);
    // m4
    k_conv<<<32*64,  256, 0, stream>>>(A, m4_w1, m4_b1, nullptr,  nullptr, B, 64,  128, 128, 1);
    k_conv<<<32*3,   256, 0, stream>>>(B, m4_w2, m4_b2, nullptr,  nullptr, C, 3,   64,  64,  0);

    k_pcd <<<32, 256, 0, stream>>>(C, out, XYZ);
    k_fps <<<32, FPS_T, 0, stream>>>(XYZ, out + 24576);
}

// Round 9
// 2138.582 us; speedup vs baseline: 1.8647x; 1.8647x over previous
//
#include <hip/hip_runtime.h>

#define NFULL 33024
#define FPS_T 512
#define BST   99072    // per-batch stride in XYZ SoA: 3*33024

// ---- x1[b,o,k] = sum_i f[b,i] * ps_w[i,o,k] + ps_b[o] ; col = o*256+k ----
__global__ void k_ps(const float* __restrict__ feat,
                     const float* __restrict__ psw,
                     const float* __restrict__ psb,
                     float* __restrict__ out)
{
    __shared__ float fs[16384];   // all of f (32x512), 64 KB
    const int tid = threadIdx.x;
    for (int k = tid; k < 16384; k += 256) fs[k] = feat[k];
    __syncthreads();
    const int col = blockIdx.x * 256 + tid;    // 0..32767
    float acc[32];
    #pragma unroll
    for (int b = 0; b < 32; ++b) acc[b] = 0.f;
    for (int i = 0; i < 512; i += 4) {
        const float w0 = psw[(i+0)*32768 + col];
        const float w1 = psw[(i+1)*32768 + col];
        const float w2 = psw[(i+2)*32768 + col];
        const float w3 = psw[(i+3)*32768 + col];
        #pragma unroll
        for (int b = 0; b < 32; ++b) {
            const float4 f4 = *(const float4*)&fs[b*512 + i];
            acc[b] += f4.x*w0 + f4.y*w1 + f4.z*w2 + f4.w*w3;
        }
    }
    const float bias = psb[col >> 8];
    #pragma unroll
    for (int b = 0; b < 32; ++b) out[b*32768 + col] = acc[b] + bias;
}

// ---- fb[wsel][b,o] = sum_{i<512} f[b,i] * w[o*640 + 128 + i]  (fr-fold) ----
__global__ void k_fb(const float* __restrict__ feat,
                     const float* __restrict__ wa, const float* __restrict__ wb,
                     const float* __restrict__ wc, const float* __restrict__ wd,
                     float* __restrict__ fb)
{
    const int tid = blockIdx.x * 256 + threadIdx.x;  // 0..16383
    const int wsel = tid >> 12;
    const int r = tid & 4095;
    const int b = r >> 7, o = r & 127;
    const float* w = (wsel == 0 ? wa : wsel == 1 ? wb : wsel == 2 ? wc : wd) + o*640 + 128;
    const float* f = feat + b*512;
    float acc = 0.f;
    for (int i = 0; i < 512; i += 4) {
        const float4 wv = *(const float4*)(w + i);
        const float4 fv = *(const float4*)(f + i);
        acc += wv.x*fv.x + wv.y*fv.y + wv.z*fv.z + wv.w*fv.w;
    }
    fb[tid] = acc;
}

// ---- out[b,o,n] = relu?( sum_i w[o,i]*x[b,i,n] + bias[o] + fb[b,o] + add[b,o,n] )
__global__ void k_conv(const float* __restrict__ x,
                       const float* __restrict__ w,
                       const float* __restrict__ bias,
                       const float* __restrict__ fb,
                       const float* __restrict__ add,
                       float* __restrict__ out,
                       const int O, const int K, const int ldw, const int relu)
{
    const int bo = blockIdx.x;
    const int b = bo / O;
    const int o = bo - b * O;
    const int n = threadIdx.x;
    const float* __restrict__ wr = w + o * ldw;
    const float* __restrict__ xb = x + (b * K) * 256 + n;
    float acc = 0.f;
    for (int i = 0; i < K; i += 4) {
        const float4 wv = *(const float4*)(wr + i);
        acc += wv.x * xb[(i+0) << 8];
        acc += wv.y * xb[(i+1) << 8];
        acc += wv.z * xb[(i+2) << 8];
        acc += wv.w * xb[(i+3) << 8];
    }
    acc += bias[o];
    if (fb)   acc += fb[b * O + o];
    if (add)  acc += add[bo * 256 + n];
    if (relu) acc = fmaxf(acc, 0.f);
    out[bo * 256 + n] = acc;
}

// ---- pcd transpose -> d_out ; completion points -> XYZ SoA [0,256) ----
__global__ void k_pcd(const float* __restrict__ comp,
                      float* __restrict__ pcd_out,
                      float* __restrict__ XYZ)
{
    const int tid = blockIdx.x * 256 + threadIdx.x;  // 0..8191
    const int b = tid >> 8, n = tid & 255;
    const float cx = comp[(b*3+0)*256 + n];
    const float cy = comp[(b*3+1)*256 + n];
    const float cz = comp[(b*3+2)*256 + n];
    pcd_out[tid*3+0] = cx; pcd_out[tid*3+1] = cy; pcd_out[tid*3+2] = cz;
    float* Xb = XYZ + b*BST;
    Xb[n]           = cx;
    Xb[33024  + n]  = cy;
    Xb[66048  + n]  = cz;
}

// ---- partial (AoS) -> XYZ SoA [256,33024) per batch (bitwise) ----
__global__ void k_copy(const float* __restrict__ partial, float* __restrict__ XYZ)
{
    const int p = blockIdx.x*256 + threadIdx.x;   // 0..1048575 (32*32768)
    const int b = p >> 15, i = p & 32767;
    const float x = partial[p*3+0];
    const float y = partial[p*3+1];
    const float z = partial[p*3+2];
    float* Xb = XYZ + b*BST;
    Xb[256 + i]          = x;
    Xb[33024 + 256 + i]  = y;
    Xb[66048 + 256 + i]  = z;
}

// ================= farthest point sampling =================
// One 512-thread block per batch. Lesson r1-r8: the allocator budgets 128
// VGPR @T=512 / 64 @T=1024 regardless of launch_bounds/waves_per_eu, and ANY
// per-thread persistent state spills. So persistent state is ZERO registers:
// the mutable d array lives in LDS (each thread RMWs only its own slots via
// ds_read_b128/ds_write_b128 -> no cross-thread hazard, no extra barrier);
// x/y/z stream from the L2-resident SoA. Registers hold only transients
// (~75), giving the compiler headroom to pipeline the 48 stream loads/step.
// Mapping p = jo*2048 + t4 + c: lane-coalesced, per-thread ascending (jo
// major, c minor) -> strict-> scan + min-index tie-break == np.argmax
// first-max exactly. Distance math bitwise-np-exact (no fma).

#define REP16(M) \
  M(0) M(1) M(2) M(3) M(4) M(5) M(6) M(7) \
  M(8) M(9) M(10) M(11) M(12) M(13) M(14) M(15)

#define FBODY(xx, yy, zz, dd, cc) { \
    const float dx = __fsub_rn((xx), lx); \
    const float dy = __fsub_rn((yy), ly); \
    const float dz = __fsub_rn((zz), lz); \
    const float dist = __fadd_rn(__fadd_rn(__fmul_rn(dx,dx), __fmul_rn(dy,dy)), \
                                 __fmul_rn(dz,dz)); \
    dd = fminf(dd, dist); \
    if (dd > bestv) { bestv = dd; bestc = (cc); } }

#define FPS_GRP(jo) { \
    const int off = (jo)*2048 + t4; \
    const float4 x4 = *(const float4*)(Xb + off); \
    const float4 y4 = *(const float4*)(Yb + off); \
    const float4 z4 = *(const float4*)(Zb + off); \
    float4 d4 = *(float4*)(dls + off); \
    FBODY(x4.x, y4.x, z4.x, d4.x, (jo)*4 + 0) \
    FBODY(x4.y, y4.y, z4.y, d4.y, (jo)*4 + 1) \
    FBODY(x4.z, y4.z, z4.z, d4.z, (jo)*4 + 2) \
    FBODY(x4.w, y4.w, z4.w, d4.w, (jo)*4 + 3) \
    *(float4*)(dls + off) = d4; }

__launch_bounds__(FPS_T)
__global__ void k_fps(const float* __restrict__ XYZ, float* __restrict__ outp)
{
    __shared__ __align__(16) float dls[NFULL];   // 132,096 B: the d array
    __shared__ float redv[2][8];
    __shared__ int   redi[2][8];

    const int b = blockIdx.x;
    const int t = threadIdx.x;
    const int t4 = t << 2;
    const float* __restrict__ Xb = XYZ + b*BST;
    const float* __restrict__ Yb = Xb + 33024;
    const float* __restrict__ Zb = Xb + 66048;
    const float NEG = -__builtin_inff();

    {   // init d = 1e10 over this thread's private slots
        const float4 v = make_float4(1.0e10f, 1.0e10f, 1.0e10f, 1.0e10f);
        #pragma unroll
        for (int jo = 0; jo < 16; ++jo) *(float4*)(dls + jo*2048 + t4) = v;
        if (t < 64) *(float4*)(dls + 32768 + t4) = v;
    }
    __syncthreads();

    int last = 0;
    float* __restrict__ po = outp + b * (512*3);
    for (int s = 0; s < 512; ++s) {
        const float lx = Xb[last];    // broadcast L2 hits
        const float ly = Yb[last];
        const float lz = Zb[last];
        if (t == 0) { po[s*3+0] = lx; po[s*3+1] = ly; po[s*3+2] = lz; }
        if (s == 511) break;

        float bestv = NEG;
        int   bestc = 0x7FFFFFFF;
        // np order: dist = (dx*dx + dy*dy) + dz*dz, no fma; strict-> scan
        REP16(FPS_GRP)
        if (t < 64) {   // tail points 32768..33023, codes 64..67
            const int off = 32768 + t4;
            const float4 x4 = *(const float4*)(Xb + off);
            const float4 y4 = *(const float4*)(Yb + off);
            const float4 z4 = *(const float4*)(Zb + off);
            float4 d4 = *(float4*)(dls + off);
            FBODY(x4.x, y4.x, z4.x, d4.x, 64)
            FBODY(x4.y, y4.y, z4.y, d4.y, 65)
            FBODY(x4.z, y4.z, z4.z, d4.z, 66)
            FBODY(x4.w, y4.w, z4.w, d4.w, 67)
            *(float4*)(dls + off) = d4;
        }
        // decode code -> global index: ((code>>2)<<11) + t4 + (code&3)
        // (code 64..67 -> (16<<11)=32768 + t4 + c : covers tail too)
        int besti = ((bestc >> 2) << 11) + t4 + (bestc & 3);

        // wave (64-lane) argmax reduce, min-index tie-break
        #pragma unroll
        for (int m = 1; m < 64; m <<= 1) {
            const float ov = __shfl_xor(bestv, m, 64);
            const int   oi = __shfl_xor(besti, m, 64);
            if (ov > bestv || (ov == bestv && oi < besti)) { bestv = ov; besti = oi; }
        }
        const int bank = s & 1;
        if ((t & 63) == 0) { redv[bank][t >> 6] = bestv; redi[bank][t >> 6] = besti; }
        __syncthreads();
        // every wave redundantly reduces the 8 partials (no 2nd barrier;
        // banks are step-parity double-buffered)
        {
            const int lane = t & 63;
            float v = (lane < 8) ? redv[bank][lane] : NEG;
            int   i = (lane < 8) ? redi[bank][lane] : 0x7FFFFFFF;
            #pragma unroll
            for (int m = 1; m < 8; m <<= 1) {
                const float ov = __shfl_xor(v, m, 64);
                const int   oi = __shfl_xor(i, m, 64);
                if (ov > v || (ov == v && oi < i)) { v = ov; i = oi; }
            }
            last = __shfl(i, 0, 64);
        }
    }
}

extern "C" void kernel_launch(void* const* d_in, const int* in_sizes, int n_in,
                              void* d_out, int out_size, void* d_ws, size_t ws_size,
                              hipStream_t stream)
{
    const float* feat    = (const float*)d_in[0];
    const float* partial = (const float*)d_in[1];
    const float* ps_w    = (const float*)d_in[2];
    const float* ps_b    = (const float*)d_in[3];
    const float* m1_w1   = (const float*)d_in[4];
    const float* m1_b1   = (const float*)d_in[5];
    const float* m1_w2   = (const float*)d_in[6];
    const float* m1_b2   = (const float*)d_in[7];
    const float* m1_ws   = (const float*)d_in[8];
    const float* m1_bs   = (const float*)d_in[9];
    const float* m2_w1   = (const float*)d_in[10];
    const float* m2_b1   = (const float*)d_in[11];
    const float* m2_w2   = (const float*)d_in[12];
    const float* m2_b2   = (const float*)d_in[13];
    const float* m2_ws   = (const float*)d_in[14];
    const float* m2_bs   = (const float*)d_in[15];
    const float* m3_w1   = (const float*)d_in[16];
    const float* m3_b1   = (const float*)d_in[17];
    const float* m3_w2   = (const float*)d_in[18];
    const float* m3_b2   = (const float*)d_in[19];
    const float* m3_ws   = (const float*)d_in[20];
    const float* m3_bs   = (const float*)d_in[21];
    const float* m4_w1   = (const float*)d_in[22];
    const float* m4_b1   = (const float*)d_in[23];
    const float* m4_w2   = (const float*)d_in[24];
    const float* m4_b2   = (const float*)d_in[25];

    float* ws = (float*)d_ws;
    float* XYZ = ws;              // 32*3*33024 = 3,170,304 floats (SoA per batch)
    float* A  = ws + 3170304;     // 1,048,576
    float* B  = ws + 4218880;     // 1,048,576
    float* C  = ws + 5267456;     // 1,048,576
    float* FB = ws + 6316032;     // 4*4096 (m1_w1, m1_ws, m3_w1, m3_ws folds)

    float* out = (float*)d_out;   // [0,24576) pcd ; [24576,73728) p0

    k_ps  <<<128,  256, 0, stream>>>(feat, ps_w, ps_b, A);
    k_fb  <<<64,   256, 0, stream>>>(feat, m1_w1, m1_ws, m3_w1, m3_ws, FB);
    k_copy<<<4096, 256, 0, stream>>>(partial, XYZ);

    // m1 (fr folded into FB)
    k_conv<<<32*128, 256, 0, stream>>>(A, m1_w1, m1_b1, FB,       nullptr, B, 128, 128, 640, 1);
    k_conv<<<32*128, 256, 0, stream>>>(A, m1_ws, m1_bs, FB+4096,  nullptr, C, 128, 128, 640, 0);
    k_conv<<<32*128, 256, 0, stream>>>(B, m1_w2, m1_b2, nullptr,  C,       A, 128, 128, 128, 0);
    // m2
    k_conv<<<32*64,  256, 0, stream>>>(A, m2_w1, m2_b1, nullptr,  nullptr, B, 64,  128, 128, 1);
    k_conv<<<32*128, 256, 0, stream>>>(A, m2_ws, m2_bs, nullptr,  nullptr, C, 128, 128, 128, 0);
    k_conv<<<32*128, 256, 0, stream>>>(B, m2_w2, m2_b2, nullptr,  C,       A, 128, 64,  64,  0);
    // m3 (fr folded)
    k_conv<<<32*128, 256, 0, stream>>>(A, m3_w1, m3_b1, FB+8192,  nullptr, B, 128, 128, 640, 1);
    k_conv<<<32*128, 256, 0, stream>>>(A, m3_ws, m3_bs, FB+12288, nullptr, C, 128, 128, 640, 0);
    k_conv<<<32*128, 256, 0, stream>>>(B, m3_w2, m3_b2, nullptr,  C,       A, 128, 128, 128, 0);
    // m4
    k_conv<<<32*64,  256, 0, stream>>>(A, m4_w1, m4_b1, nullptr,  nullptr, B, 64,  128, 128, 1);
    k_conv<<<32*3,   256, 0, stream>>>(B, m4_w2, m4_b2, nullptr,  nullptr, C, 3,   64,  64,  0);

    k_pcd <<<32, 256, 0, stream>>>(C, out, XYZ);
    k_fps <<<32, FPS_T, 0, stream>>>(XYZ, out + 24576);
}